// Round 13
// baseline (297.829 us; speedup 1.0000x reference)
//
#include <hip/hip_runtime.h>
#include <cstddef>

#define N_NODES_C 50000
#define N_EDGES_C 800000

typedef _Float16 f16x8 __attribute__((ext_vector_type(8)));
typedef float    f32x4 __attribute__((ext_vector_type(4)));

constexpr int XSTR = 72;           // f16 stride for per-wave h buffer
constexpr int FILL_BLOCKS = 1563;  // ceil(800000/512), 2 edges/thread
constexpr int QSCALE_BLOCKS = 782; // 200000 threads, 8 floats each

// ---------------------------------------------------------------------------
// prep: wT[l][j][k] = W_l[k][j] (f16); W3T[r=y*64+x][k] = w_out[k*2048+r]
// (PLAIN layout — phase 2 reads it from global, no LDS swizzle needed).
// ---------------------------------------------------------------------------
__global__ void prep_kernel(const float* __restrict__ w_in,
                            const float* __restrict__ w_mid,
                            const float* __restrict__ w_out,
                            _Float16* __restrict__ wT,
                            _Float16* __restrict__ W3T)
{
    const int idx = blockIdx.x * 256 + threadIdx.x;
    if (idx < 7 * 4096) {
        const int l = idx >> 12, rem = idx & 4095;
        const int j = rem >> 6, k = rem & 63;
        const float v = (l == 0) ? w_in[k * 64 + j]
                                 : w_mid[(size_t)(l - 1) * 4096 + k * 64 + j];
        wT[(size_t)l * 4096 + j * 64 + k] = (_Float16)v;
    } else if (idx < 159744) {
        const int i2 = idx - 7 * 4096;   // < 131072
        const int r = i2 >> 6, k = i2 & 63;
        W3T[(size_t)r * 64 + k] = (_Float16)w_out[(size_t)k * 2048 + r];
    }
}

// ---------------------------------------------------------------------------
// MEGA kernel, grid (391, 2). Per block: 128 nodes, y-half = blockIdx.y*16.
//  Step 0: deg piggyback — 1024 edges/block of fire-and-forget atomics
//          (no dependency -> fully hidden behind compute).
//  Phase 1: per-wave MLP (wave-private hb LDS, ZERO barriers).
//  Phase 2: qcalc over 16 y. A-frags stream from global W3T with register
//          double-buffering (prefetch y+1 while computing y). No LDS, no
//          barriers. Stores RAW q (dinv applied later in fill_qscale).
// ---------------------------------------------------------------------------
__launch_bounds__(256, 3)
__global__ void mega_kernel(const float* __restrict__ xf,
                            const float* __restrict__ b_in,
                            const float* __restrict__ b_mid,
                            const _Float16* __restrict__ wT,
                            const _Float16* __restrict__ W3T,
                            const float* __restrict__ b_out,
                            const int* __restrict__ col,
                            int* __restrict__ deg,
                            float* __restrict__ qs)
{
    __shared__ _Float16 hball[4][32 * XSTR];   // 4 x 4608 B = 18432 B

    const int t    = threadIdx.x;
    const int w    = t >> 6;
    const int lane = t & 63;
    const int quad = lane >> 4;
    const int lrow = lane & 15;

    // ---- step 0: deg atomics (fire-and-forget) ----
    {
        const int bid = blockIdx.y * 391 + blockIdx.x;
        const int e0 = bid * 1024 + t;
        #pragma unroll
        for (int k = 0; k < 4; ++k) {
            const int e = e0 + k * 256;
            if (e < N_EDGES_C) atomicAdd(&deg[col[e]], 1);
        }
    }

    const int node0 = blockIdx.x * 128 + w * 32;
    _Float16* hb = hball[w];

    // ---- phase 1a: stage x -> f16 hb (2 groups of 16 nodes) ----
    #pragma unroll
    for (int g = 0; g < 2; ++g) {
        const int nl = g * 16 + lrow;
        const int n = min(node0 + nl, N_NODES_C - 1);
        const float4* src4 = (const float4*)(xf + (size_t)n * 64 + quad * 16);
        _Float16 tmp[16];
        #pragma unroll
        for (int i = 0; i < 4; ++i) {
            const float4 v = src4[i];
            tmp[i * 4 + 0] = (_Float16)v.x;
            tmp[i * 4 + 1] = (_Float16)v.y;
            tmp[i * 4 + 2] = (_Float16)v.z;
            tmp[i * 4 + 3] = (_Float16)v.w;
        }
        *(f16x8*)&hb[nl * XSTR + quad * 16]     = *(f16x8*)&tmp[0];
        *(f16x8*)&hb[nl * XSTR + quad * 16 + 8] = *(f16x8*)&tmp[8];
    }

    // ---- phase 1b: 7 layers, wave-private, 32 nodes/wave ----
    {
        const _Float16* wTl = wT;
        const float* bsrc = b_in;
        for (int l = 0; l < 7; ++l) {
            const f16x8 A0a = *(const f16x8*)&hb[lrow * XSTR + quad * 8];
            const f16x8 A1a = *(const f16x8*)&hb[lrow * XSTR + 32 + quad * 8];
            const f16x8 A0b = *(const f16x8*)&hb[(16 + lrow) * XSTR + quad * 8];
            const f16x8 A1b = *(const f16x8*)&hb[(16 + lrow) * XSTR + 32 + quad * 8];
            #pragma unroll
            for (int Nt = 0; Nt < 4; ++Nt) {
                const f16x8 B0 = *(const f16x8*)(wTl + (Nt * 16 + lrow) * 64 + quad * 8);
                const f16x8 B1 = *(const f16x8*)(wTl + (Nt * 16 + lrow) * 64 + 32 + quad * 8);
                const float bias = bsrc[Nt * 16 + lrow];
                f32x4 Ca = {0.f, 0.f, 0.f, 0.f};
                Ca = __builtin_amdgcn_mfma_f32_16x16x32_f16(A0a, B0, Ca, 0, 0, 0);
                Ca = __builtin_amdgcn_mfma_f32_16x16x32_f16(A1a, B1, Ca, 0, 0, 0);
                f32x4 Cb = {0.f, 0.f, 0.f, 0.f};
                Cb = __builtin_amdgcn_mfma_f32_16x16x32_f16(A0b, B0, Cb, 0, 0, 0);
                Cb = __builtin_amdgcn_mfma_f32_16x16x32_f16(A1b, B1, Cb, 0, 0, 0);
                #pragma unroll
                for (int r = 0; r < 4; ++r) {
                    const float va = fmaxf(Ca[r] + bias, 0.f);
                    const float vb = fmaxf(Cb[r] + bias, 0.f);
                    hb[(quad * 4 + r) * XSTR + Nt * 16 + lrow]      = (_Float16)va;
                    hb[(16 + quad * 4 + r) * XSTR + Nt * 16 + lrow] = (_Float16)vb;
                }
            }
            wTl += 4096;
            bsrc = b_mid + (size_t)l * 64;
        }
    }

    // ---- phase 2 setup ----
    const int ra = node0 + lrow;
    const int rb = node0 + 16 + lrow;
    const int na = min(ra, N_NODES_C - 1);
    const int nb = min(rb, N_NODES_C - 1);

    f16x8 Bha[2], Bhb[2];
    #pragma unroll
    for (int ks = 0; ks < 2; ++ks) {
        Bha[ks] = *(const f16x8*)&hb[lrow * XSTR + ks * 32 + quad * 8];
        Bhb[ks] = *(const f16x8*)&hb[(16 + lrow) * XSTR + ks * 32 + quad * 8];
    }
    float4 xca[4], xcb[4];
    #pragma unroll
    for (int xt = 0; xt < 4; ++xt) {
        xca[xt] = *(const float4*)(xf + (size_t)na * 64 + xt * 16 + quad * 4);
        xcb[xt] = *(const float4*)(xf + (size_t)nb * 64 + xt * 16 + quad * 4);
    }

    const int y0 = blockIdx.y * 16;
    // lane-base pointer into W3T; frag (xt,ks) at + xt*1024 + ks*32 (f16 units)
    const _Float16* Wbase = W3T + (size_t)y0 * 4096 + (size_t)lrow * 64 + quad * 8;

    // prefetch y0's 8 A-frags
    f16x8 A[8];
    #pragma unroll
    for (int xt = 0; xt < 4; ++xt)
        #pragma unroll
        for (int ks = 0; ks < 2; ++ks)
            A[xt * 2 + ks] = *(const f16x8*)(Wbase + xt * 1024 + ks * 32);

    // ---- phase 2: 16 y, register double-buffered A-frags, no barriers ----
    #pragma unroll 2
    for (int yy = 0; yy < 16; ++yy) {
        const int y = y0 + yy;
        const bool more = (yy + 1 < 16);
        f16x8 An[8];
        if (more) {
            const _Float16* Wn = Wbase + (size_t)(yy + 1) * 4096;
            #pragma unroll
            for (int xt = 0; xt < 4; ++xt)
                #pragma unroll
                for (int ks = 0; ks < 2; ++ks)
                    An[xt * 2 + ks] = *(const f16x8*)(Wn + xt * 1024 + ks * 32);
        }

        float qa = 0.f, qb = 0.f;
        #pragma unroll
        for (int xt = 0; xt < 4; ++xt) {
            f32x4 Ca = {0.f, 0.f, 0.f, 0.f};
            Ca = __builtin_amdgcn_mfma_f32_16x16x32_f16(A[xt * 2],     Bha[0], Ca, 0, 0, 0);
            Ca = __builtin_amdgcn_mfma_f32_16x16x32_f16(A[xt * 2 + 1], Bha[1], Ca, 0, 0, 0);
            f32x4 Cb = {0.f, 0.f, 0.f, 0.f};
            Cb = __builtin_amdgcn_mfma_f32_16x16x32_f16(A[xt * 2],     Bhb[0], Cb, 0, 0, 0);
            Cb = __builtin_amdgcn_mfma_f32_16x16x32_f16(A[xt * 2 + 1], Bhb[1], Cb, 0, 0, 0);

            const float4 bf = *(const float4*)(b_out + y * 64 + xt * 16 + quad * 4);
            qa += (Ca[0] + bf.x) * xca[xt].x + (Ca[1] + bf.y) * xca[xt].y
                + (Ca[2] + bf.z) * xca[xt].z + (Ca[3] + bf.w) * xca[xt].w;
            qb += (Cb[0] + bf.x) * xcb[xt].x + (Cb[1] + bf.y) * xcb[xt].y
                + (Cb[2] + bf.z) * xcb[xt].z + (Cb[3] + bf.w) * xcb[xt].w;
        }
        qa += __shfl_xor(qa, 16);
        qa += __shfl_xor(qa, 32);
        qb += __shfl_xor(qb, 16);
        qb += __shfl_xor(qb, 32);

        if (quad == (y >> 3)) {               // quad q stores y in [8q, 8q+8)
            if (ra < N_NODES_C) qs[(size_t)ra * 32 + y] = qa;   // raw (dinv later)
            if (rb < N_NODES_C) qs[(size_t)rb * 32 + y] = qb;
        }

        if (more) {
            #pragma unroll
            for (int i = 0; i < 8; ++i) A[i] = An[i];
        }
    }
}

// ---------------------------------------------------------------------------
// 3-phase parallel scan; scan3 also emits dinv.
// ---------------------------------------------------------------------------
__global__ void scan1_kernel(const int* __restrict__ deg, int* __restrict__ bsum)
{
    const int t = threadIdx.x;
    const int i = blockIdx.x * 256 + t;
    int v = (i < N_NODES_C) ? deg[i] : 0;
    #pragma unroll
    for (int d = 1; d < 64; d <<= 1) v += __shfl_xor(v, d);
    __shared__ int s[4];
    if ((t & 63) == 0) s[t >> 6] = v;
    __syncthreads();
    if (t == 0) bsum[blockIdx.x] = s[0] + s[1] + s[2] + s[3];
}

__global__ void scan2_kernel(const int* __restrict__ bsum, int* __restrict__ boff,
                             int* __restrict__ rowptr)
{
    __shared__ int sh[256];
    const int t = threadIdx.x;
    const int v = (t < 196) ? bsum[t] : 0;
    sh[t] = v;
    __syncthreads();
    for (int d = 1; d < 256; d <<= 1) {
        const int u = (t >= d) ? sh[t - d] : 0;
        __syncthreads();
        sh[t] += u;
        __syncthreads();
    }
    if (t < 196) boff[t] = sh[t] - v;     // exclusive
    if (t == 0) rowptr[N_NODES_C] = N_EDGES_C;
}

__global__ void scan3_kernel(const int* __restrict__ deg, const int* __restrict__ boff,
                             int* __restrict__ rowptr, int* __restrict__ pos,
                             float* __restrict__ dinv)
{
    const int t = threadIdx.x;
    const int i = blockIdx.x * 256 + t;
    const int lane = t & 63, w = t >> 6;
    const int v = (i < N_NODES_C) ? deg[i] : 0;
    int inc = v;
    #pragma unroll
    for (int d = 1; d < 64; d <<= 1) {
        const int u = __shfl_up(inc, d);
        if (lane >= d) inc += u;
    }
    __shared__ int ws[4];
    if (lane == 63) ws[w] = inc;
    __syncthreads();
    int wo = 0;
    #pragma unroll
    for (int k = 0; k < 4; ++k) if (k < w) wo += ws[k];
    const int excl = boff[blockIdx.x] + wo + inc - v;
    if (i < N_NODES_C) {
        rowptr[i] = excl;
        pos[i] = excl;
        dinv[i] = (v > 0) ? rsqrtf((float)v) : 0.f;
    }
}

// ---------------------------------------------------------------------------
// Fused: blocks [0, FILL_BLOCKS) = CSR fill (2 edges/thread);
// blocks >= FILL_BLOCKS = qscale: qs[n,y] *= dinv[n] (8 floats/thread).
// ---------------------------------------------------------------------------
__global__ void fill_qscale_kernel(const int* __restrict__ row,
                                   const int* __restrict__ col,
                                   int* __restrict__ pos,
                                   int* __restrict__ src,
                                   float* __restrict__ qs,
                                   const float* __restrict__ dinv)
{
    const int t = threadIdx.x;
    if (blockIdx.x < FILL_BLOCKS) {
        const int e0 = blockIdx.x * 512 + t;
        const int e1 = e0 + 256;
        if (e0 < N_EDGES_C) {
            const int slot = atomicAdd(&pos[col[e0]], 1);
            src[slot] = row[e0];
        }
        if (e1 < N_EDGES_C) {
            const int slot = atomicAdd(&pos[col[e1]], 1);
            src[slot] = row[e1];
        }
    } else {
        const int i = (blockIdx.x - FILL_BLOCKS) * 256 + t;   // 8 floats each
        if (i < N_NODES_C * 4) {
            const int n = i >> 2;
            const float f = dinv[n];
            float4* p = (float4*)(qs + (size_t)i * 8);
            float4 v0 = p[0], v1 = p[1];
            v0.x *= f; v0.y *= f; v0.z *= f; v0.w *= f;
            v1.x *= f; v1.y *= f; v1.z *= f; v1.w *= f;
            p[0] = v0; p[1] = v1;
        }
    }
}

// ---------------------------------------------------------------------------
// Gather: out[n,y] = dinv[n] * sum_{s in CSR row n} qs[src[s], y]
// ---------------------------------------------------------------------------
__global__ void gather_kernel(const int* __restrict__ rowptr, const int* __restrict__ src,
                              const float* __restrict__ qs, const float* __restrict__ dinv,
                              float* __restrict__ out)
{
    const int t = threadIdx.x;
    const int node = blockIdx.x * 8 + (t >> 5);
    const int y = t & 31;
    const int s0 = rowptr[node];
    const int s1 = rowptr[node + 1];
    float acc = 0.f;
    int s = s0;
    for (; s + 4 <= s1; s += 4) {
        const int r0 = src[s], r1 = src[s + 1], r2 = src[s + 2], r3 = src[s + 3];
        acc += qs[(size_t)r0 * 32 + y];
        acc += qs[(size_t)r1 * 32 + y];
        acc += qs[(size_t)r2 * 32 + y];
        acc += qs[(size_t)r3 * 32 + y];
    }
    for (; s < s1; ++s) acc += qs[(size_t)src[s] * 32 + y];
    out[(size_t)node * 32 + y] = acc * dinv[node];
}

// ---------------------------------------------------------------------------
extern "C" void kernel_launch(void* const* d_in, const int* in_sizes, int n_in,
                              void* d_out, int out_size, void* d_ws, size_t ws_size,
                              hipStream_t stream)
{
    const float* xf    = (const float*)d_in[0];
    const int*   eidx  = (const int*)d_in[1];
    const float* w_in  = (const float*)d_in[2];
    const float* b_in  = (const float*)d_in[3];
    const float* w_mid = (const float*)d_in[4];
    const float* b_mid = (const float*)d_in[5];
    const float* w_out = (const float*)d_in[6];
    const float* b_out = (const float*)d_in[7];
    float* out = (float*)d_out;

    const int* row = eidx;
    const int* col = eidx + N_EDGES_C;

    // workspace layout (bytes)
    char* ws = (char*)d_ws;
    float*    qs     = (float*)(ws + 0);            //  6,400,000
    int*      deg    = (int*)(ws + 6400000);        //    200,000
    float*    dinv   = (float*)(ws + 6600000);      //    200,000
    _Float16* wT     = (_Float16*)(ws + 6800000);   //     57,344
    _Float16* W3T    = (_Float16*)(ws + 6857344);   //    262,144
    int*      rowptr = (int*)(ws + 7119488);        //    200,004
    int*      pos    = (int*)(ws + 7319492);        //    200,000
    int*      srcb   = (int*)(ws + 7519492);        //  3,200,000
    int*      bsum   = (int*)(ws + 10719492);       //        784
    int*      boff   = (int*)(ws + 10720276);       //        784

    hipMemsetAsync(deg, 0, N_NODES_C * sizeof(int), stream);

    prep_kernel<<<dim3(624), dim3(256), 0, stream>>>(w_in, w_mid, w_out, wT, W3T);

    mega_kernel<<<dim3(391, 2), dim3(256), 0, stream>>>(
        xf, b_in, b_mid, wT, W3T, b_out, col, deg, qs);

    scan1_kernel<<<dim3(196), dim3(256), 0, stream>>>(deg, bsum);
    scan2_kernel<<<dim3(1), dim3(256), 0, stream>>>(bsum, boff, rowptr);
    scan3_kernel<<<dim3(196), dim3(256), 0, stream>>>(deg, boff, rowptr, pos, dinv);

    fill_qscale_kernel<<<dim3(FILL_BLOCKS + QSCALE_BLOCKS), dim3(256), 0, stream>>>(
        row, col, pos, srcb, qs, dinv);

    gather_kernel<<<dim3(N_NODES_C / 8), dim3(256), 0, stream>>>(rowptr, srcb, qs, dinv, out);
}

// Round 14
// 215.759 us; speedup vs baseline: 1.3804x; 1.3804x over previous
//
#include <hip/hip_runtime.h>
#include <cstddef>

#define N_NODES_C 50000
#define N_EDGES_C 800000

typedef _Float16 f16x8 __attribute__((ext_vector_type(8)));
typedef float    f32x4 __attribute__((ext_vector_type(4)));

constexpr int XSTR = 72;           // f16 stride for per-wave h buffer
constexpr int MQ_BLOCKS   = 782;   // ceil(50000/64) compute blocks in mega
constexpr int FILL_BLOCKS = 1563;  // ceil(800000/512), 2 edges/thread
constexpr int DEG_BLOCKS  = 782;   // ceil(800000/1024), 4 edges/thread

// ---------------------------------------------------------------------------
// prep (wT, W3T swizzled) + deg fused (4 shadow arrays, 4 edges/thread).
//  wT[l][j][k] = W_l[k][j] (f16)                      idx [0, 28672)
//  W3T[r=y*64+x][64 k] (f16), 16B chunks XOR-swizzled: chunk c of row r
//  stored at chunk c^(r&7). Value = w_out[k*2048 + r].   idx [28672, 159744)
// ---------------------------------------------------------------------------
__global__ void prep_deg_kernel(const float* __restrict__ w_in,
                                const float* __restrict__ w_mid,
                                const float* __restrict__ w_out,
                                const int* __restrict__ col,
                                _Float16* __restrict__ wT,
                                _Float16* __restrict__ W3T,
                                int* __restrict__ deg4)   // [4][N_NODES_C]
{
    const int b = blockIdx.x;
    if (b < 624) {
        const int idx = b * 256 + threadIdx.x;
        if (idx < 7 * 4096) {
            const int l = idx >> 12, rem = idx & 4095;
            const int j = rem >> 6, k = rem & 63;
            const float v = (l == 0) ? w_in[k * 64 + j]
                                     : w_mid[(size_t)(l - 1) * 4096 + k * 64 + j];
            wT[(size_t)l * 4096 + j * 64 + k] = (_Float16)v;
        } else {
            const int i2 = idx - 7 * 4096;   // < 131072
            const int r = i2 >> 6, k = i2 & 63;
            const int c = k >> 3;
            const int pos = ((c ^ (r & 7)) << 3) | (k & 7);
            W3T[(size_t)r * 64 + pos] = (_Float16)w_out[(size_t)k * 2048 + r];
        }
    } else {
        const int e0 = (b - 624) * 1024 + threadIdx.x;
        #pragma unroll
        for (int k = 0; k < 4; ++k) {
            const int e = e0 + k * 256;
            if (e < N_EDGES_C)
                atomicAdd(&deg4[k * N_NODES_C + col[e]], 1);
        }
    }
}

// ---------------------------------------------------------------------------
// 3-phase parallel scan over deg = sum of 4 shadows; scan3 also emits dinv.
// ---------------------------------------------------------------------------
__global__ void scan1_kernel(const int* __restrict__ deg4, int* __restrict__ bsum)
{
    const int t = threadIdx.x;
    const int i = blockIdx.x * 256 + t;
    int v = 0;
    if (i < N_NODES_C) {
        #pragma unroll
        for (int k = 0; k < 4; ++k) v += deg4[k * N_NODES_C + i];
    }
    #pragma unroll
    for (int d = 1; d < 64; d <<= 1) v += __shfl_xor(v, d);
    __shared__ int s[4];
    if ((t & 63) == 0) s[t >> 6] = v;
    __syncthreads();
    if (t == 0) bsum[blockIdx.x] = s[0] + s[1] + s[2] + s[3];
}

__global__ void scan2_kernel(const int* __restrict__ bsum, int* __restrict__ boff,
                             int* __restrict__ rowptr)
{
    __shared__ int sh[256];
    const int t = threadIdx.x;
    const int v = (t < 196) ? bsum[t] : 0;
    sh[t] = v;
    __syncthreads();
    for (int d = 1; d < 256; d <<= 1) {
        const int u = (t >= d) ? sh[t - d] : 0;
        __syncthreads();
        sh[t] += u;
        __syncthreads();
    }
    if (t < 196) boff[t] = sh[t] - v;     // exclusive
    if (t == 0) rowptr[N_NODES_C] = N_EDGES_C;
}

__global__ void scan3_kernel(const int* __restrict__ deg4, const int* __restrict__ boff,
                             int* __restrict__ rowptr, int* __restrict__ pos,
                             float* __restrict__ dinv)
{
    const int t = threadIdx.x;
    const int i = blockIdx.x * 256 + t;
    const int lane = t & 63, w = t >> 6;
    int v = 0;
    if (i < N_NODES_C) {
        #pragma unroll
        for (int k = 0; k < 4; ++k) v += deg4[k * N_NODES_C + i];
    }
    int inc = v;
    #pragma unroll
    for (int d = 1; d < 64; d <<= 1) {
        const int u = __shfl_up(inc, d);
        if (lane >= d) inc += u;
    }
    __shared__ int ws[4];
    if (lane == 63) ws[w] = inc;
    __syncthreads();
    int wo = 0;
    #pragma unroll
    for (int k = 0; k < 4; ++k) if (k < w) wo += ws[k];
    const int excl = boff[blockIdx.x] + wo + inc - v;
    if (i < N_NODES_C) {
        rowptr[i] = excl;
        pos[i] = excl;
        dinv[i] = (v > 0) ? rsqrtf((float)v) : 0.f;
    }
}

// ---------------------------------------------------------------------------
// MEGA kernel.
//  Blocks [0, MQ_BLOCKS): 64 nodes each, 4 waves x 16 nodes.
//    Phase 1: per-wave MLP (wave-private hb LDS, zero barriers).
//    Phase 2: qcalc over all 32 y (double-buffered swizzled W3T slices in
//    shared LDS); h B-frags from the wave's own hb. Stores qa*dinv.
//  Blocks >= MQ_BLOCKS: CSR fill (2 edges/thread).
//  782 compute blocks (~3-6/CU) so phase-2 barriers overlap across blocks.
// ---------------------------------------------------------------------------
__launch_bounds__(256, 4)
__global__ void mega_kernel(const float* __restrict__ xf,
                            const float* __restrict__ b_in,
                            const float* __restrict__ b_mid,
                            const _Float16* __restrict__ wT,
                            const _Float16* __restrict__ W3T,
                            const float* __restrict__ b_out,
                            const float* __restrict__ dinv,
                            float* __restrict__ qs,
                            const int* __restrict__ row,
                            const int* __restrict__ col,
                            int* __restrict__ pos,
                            int* __restrict__ src)
{
    __shared__ _Float16 hball[4][16 * XSTR];   // 4 x 2304 B = 9216 B
    __shared__ _Float16 ws3[2][4096];          // 16384 B

    if (blockIdx.x >= MQ_BLOCKS) {
        // ---------------- fill part ----------------
        const int e0 = (blockIdx.x - MQ_BLOCKS) * 512 + threadIdx.x;
        const int e1 = e0 + 256;
        if (e0 < N_EDGES_C) {
            const int slot = atomicAdd(&pos[col[e0]], 1);
            src[slot] = row[e0];
        }
        if (e1 < N_EDGES_C) {
            const int slot = atomicAdd(&pos[col[e1]], 1);
            src[slot] = row[e1];
        }
        return;
    }

    const int t    = threadIdx.x;
    const int w    = t >> 6;
    const int lane = t & 63;
    const int quad = lane >> 4;
    const int lrow = lane & 15;
    const int node0 = blockIdx.x * 64 + w * 16;
    _Float16* hb = hball[w];

    // ---- phase 1a: stage x -> f16 hb ----
    {
        const int n = min(node0 + lrow, N_NODES_C - 1);
        const float4* src4 = (const float4*)(xf + (size_t)n * 64 + quad * 16);
        _Float16 tmp[16];
        #pragma unroll
        for (int i = 0; i < 4; ++i) {
            const float4 v = src4[i];
            tmp[i * 4 + 0] = (_Float16)v.x;
            tmp[i * 4 + 1] = (_Float16)v.y;
            tmp[i * 4 + 2] = (_Float16)v.z;
            tmp[i * 4 + 3] = (_Float16)v.w;
        }
        *(f16x8*)&hb[lrow * XSTR + quad * 16]     = *(f16x8*)&tmp[0];
        *(f16x8*)&hb[lrow * XSTR + quad * 16 + 8] = *(f16x8*)&tmp[8];
    }

    // ---- phase 1b: 7 layers, wave-private, 16 nodes/wave ----
    {
        const _Float16* wTl = wT;
        const float* bsrc = b_in;
        for (int l = 0; l < 7; ++l) {
            const f16x8 A0 = *(const f16x8*)&hb[lrow * XSTR + quad * 8];
            const f16x8 A1 = *(const f16x8*)&hb[lrow * XSTR + 32 + quad * 8];
            #pragma unroll
            for (int Nt = 0; Nt < 4; ++Nt) {
                const f16x8 B0 = *(const f16x8*)(wTl + (Nt * 16 + lrow) * 64 + quad * 8);
                const f16x8 B1 = *(const f16x8*)(wTl + (Nt * 16 + lrow) * 64 + 32 + quad * 8);
                const float bias = bsrc[Nt * 16 + lrow];
                f32x4 C = {0.f, 0.f, 0.f, 0.f};
                C = __builtin_amdgcn_mfma_f32_16x16x32_f16(A0, B0, C, 0, 0, 0);
                C = __builtin_amdgcn_mfma_f32_16x16x32_f16(A1, B1, C, 0, 0, 0);
                #pragma unroll
                for (int r = 0; r < 4; ++r) {
                    const float v = fmaxf(C[r] + bias, 0.f);
                    hb[(quad * 4 + r) * XSTR + Nt * 16 + lrow] = (_Float16)v;
                }
            }
            wTl += 4096;
            bsrc = b_mid + (size_t)l * 64;
        }
    }

    // ---- phase 2 setup: B-frags (h) from wave-private LDS ----
    const int ra = node0 + lrow;
    const int na = min(ra, N_NODES_C - 1);

    f16x8 Bha[2];
    #pragma unroll
    for (int ks = 0; ks < 2; ++ks)
        Bha[ks] = *(const f16x8*)&hb[lrow * XSTR + ks * 32 + quad * 8];
    float4 xca[4];
    #pragma unroll
    for (int xt = 0; xt < 4; ++xt)
        xca[xt] = *(const float4*)(xf + (size_t)na * 64 + xt * 16 + quad * 4);
    const float dva = dinv[na];

    // prefetch slice y=0 (dense copy preserves the global-side swizzle)
    {
        const f16x8 v0 = *(const f16x8*)(W3T + (size_t)t * 8);
        const f16x8 v1 = *(const f16x8*)(W3T + (size_t)(t + 256) * 8);
        *(f16x8*)(&ws3[0][t * 8]) = v0;
        *(f16x8*)(&ws3[0][(t + 256) * 8]) = v1;
    }

    const int swz = lrow & 7;
    const int cp0 = ((quad)     ^ swz) * 8;   // ks=0 chunk offset (f16)
    const int cp1 = ((4 + quad) ^ swz) * 8;   // ks=1 chunk offset

    __syncthreads();

    // ---- phase 2: qcalc over all 32 y (double-buffered W3T slices) ----
    for (int y = 0; y < 32; ++y) {
        f16x8 nv0, nv1;
        if (y + 1 < 32) {
            nv0 = *(const f16x8*)(W3T + (size_t)(y + 1) * 4096 + t * 8);
            nv1 = *(const f16x8*)(W3T + (size_t)(y + 1) * 4096 + (t + 256) * 8);
        }

        const _Float16* cur = ws3[y & 1];
        float qa = 0.f;
        #pragma unroll
        for (int xt = 0; xt < 4; ++xt) {
            const _Float16* rp = cur + (xt * 16 + lrow) * 64;
            const f16x8 A0 = *(const f16x8*)(rp + cp0);
            const f16x8 A1 = *(const f16x8*)(rp + cp1);
            f32x4 Ca = {0.f, 0.f, 0.f, 0.f};
            Ca = __builtin_amdgcn_mfma_f32_16x16x32_f16(A0, Bha[0], Ca, 0, 0, 0);
            Ca = __builtin_amdgcn_mfma_f32_16x16x32_f16(A1, Bha[1], Ca, 0, 0, 0);

            const float4 bf = *(const float4*)(b_out + y * 64 + xt * 16 + quad * 4);
            qa += (Ca[0] + bf.x) * xca[xt].x + (Ca[1] + bf.y) * xca[xt].y
                + (Ca[2] + bf.z) * xca[xt].z + (Ca[3] + bf.w) * xca[xt].w;
        }
        qa += __shfl_xor(qa, 16);
        qa += __shfl_xor(qa, 32);

        if (quad == (y >> 3)) {               // quad q stores y in [8q, 8q+8)
            if (ra < N_NODES_C) qs[(size_t)ra * 32 + y] = qa * dva;
        }

        if (y + 1 < 32) {
            _Float16* nxt = ws3[(y + 1) & 1];
            *(f16x8*)(&nxt[t * 8]) = nv0;
            *(f16x8*)(&nxt[(t + 256) * 8]) = nv1;
        }
        __syncthreads();
    }
}

// ---------------------------------------------------------------------------
// Gather: out[n,y] = dinv[n] * sum_{s in CSR row n} qs[src[s], y]
// ---------------------------------------------------------------------------
__global__ void gather_kernel(const int* __restrict__ rowptr, const int* __restrict__ src,
                              const float* __restrict__ qs, const float* __restrict__ dinv,
                              float* __restrict__ out)
{
    const int t = threadIdx.x;
    const int node = blockIdx.x * 8 + (t >> 5);
    const int y = t & 31;
    const int s0 = rowptr[node];
    const int s1 = rowptr[node + 1];
    float acc = 0.f;
    int s = s0;
    for (; s + 4 <= s1; s += 4) {
        const int r0 = src[s], r1 = src[s + 1], r2 = src[s + 2], r3 = src[s + 3];
        acc += qs[(size_t)r0 * 32 + y];
        acc += qs[(size_t)r1 * 32 + y];
        acc += qs[(size_t)r2 * 32 + y];
        acc += qs[(size_t)r3 * 32 + y];
    }
    for (; s < s1; ++s) acc += qs[(size_t)src[s] * 32 + y];
    out[(size_t)node * 32 + y] = acc * dinv[node];
}

// ---------------------------------------------------------------------------
extern "C" void kernel_launch(void* const* d_in, const int* in_sizes, int n_in,
                              void* d_out, int out_size, void* d_ws, size_t ws_size,
                              hipStream_t stream)
{
    const float* xf    = (const float*)d_in[0];
    const int*   eidx  = (const int*)d_in[1];
    const float* w_in  = (const float*)d_in[2];
    const float* b_in  = (const float*)d_in[3];
    const float* w_mid = (const float*)d_in[4];
    const float* b_mid = (const float*)d_in[5];
    const float* w_out = (const float*)d_in[6];
    const float* b_out = (const float*)d_in[7];
    float* out = (float*)d_out;

    const int* row = eidx;
    const int* col = eidx + N_EDGES_C;

    // workspace layout (bytes)
    char* ws = (char*)d_ws;
    float*    qs     = (float*)(ws + 0);            //  6,400,000
    int*      deg4   = (int*)(ws + 6400000);        //    800,000 (4 shadows)
    float*    dinv   = (float*)(ws + 7200000);      //    200,000
    _Float16* wT     = (_Float16*)(ws + 7400000);   //     57,344
    _Float16* W3T    = (_Float16*)(ws + 7457344);   //    262,144
    int*      rowptr = (int*)(ws + 7719488);        //    200,004
    int*      pos    = (int*)(ws + 7919492);        //    200,000
    int*      srcb   = (int*)(ws + 8119492);        //  3,200,000
    int*      bsum   = (int*)(ws + 11319492);       //        784
    int*      boff   = (int*)(ws + 11320276);       //        784

    hipMemsetAsync(deg4, 0, 4 * N_NODES_C * sizeof(int), stream);

    prep_deg_kernel<<<dim3(624 + DEG_BLOCKS), dim3(256), 0, stream>>>(
        w_in, w_mid, w_out, col, wT, W3T, deg4);

    scan1_kernel<<<dim3(196), dim3(256), 0, stream>>>(deg4, bsum);
    scan2_kernel<<<dim3(1), dim3(256), 0, stream>>>(bsum, boff, rowptr);
    scan3_kernel<<<dim3(196), dim3(256), 0, stream>>>(deg4, boff, rowptr, pos, dinv);

    mega_kernel<<<dim3(MQ_BLOCKS + FILL_BLOCKS), dim3(256), 0, stream>>>(
        xf, b_in, b_mid, wT, W3T, b_out, dinv, qs, row, col, pos, srcb);

    gather_kernel<<<dim3(N_NODES_C / 8), dim3(256), 0, stream>>>(rowptr, srcb, qs, dinv, out);
}